// Round 2
// baseline (168.166 us; speedup 1.0000x reference)
//
#include <hip/hip_runtime.h>

// Problem: out[h,k,v] = 0.95*M[h,k,v] + sum_{b,s} rho[b,s]*K[b,s,h,k]*V[b,s,h,v]
// B=4, S=4096 (ROWS=16384), H=16, Dk=Dv=64. fp32 throughout (no fp32 MFMA on CDNA4).
//
// Structure (R2): barrier-free main loop. Each block = 4 waves; each wave owns a
// private 64-row s-slice and a private LDS double-buffer (2x2KB K + 2x2KB V).
// 8x8 per-thread outer-product accumulator (one wave spans the full 64x64 tile):
// 64 FMA per 4 ds_read_b128. Cross-wave reduction + global atomics in epilogue.

constexpr int HH = 16;
constexpr int DK = 64;
constexpr int DV = 64;
constexpr int ROWS = 16384;            // B*S
constexpr int NCHUNK = 64;             // grid.x
constexpr int RPB = ROWS / NCHUNK;     // 256 rows per block
constexpr int RPW = RPB / 4;           // 64 rows per wave
constexpr int TR = 8;                  // rows per staged tile (per wave)
constexpr int NT = RPW / TR;           // 8 tiles per wave
constexpr float DECAY = 0.95f;

__global__ __launch_bounds__(256) void init_out(const float* __restrict__ mem,
                                                float* __restrict__ out) {
    int i = blockIdx.x * 256 + threadIdx.x;
    out[i] = DECAY * mem[i];
}

__global__ __launch_bounds__(256, 4) void accum(const float* __restrict__ keys,
                                                const float* __restrict__ values,
                                                const float* __restrict__ rho,
                                                float* __restrict__ out) {
    // 32 KiB: [0,4096) = K area (4 waves x 2 bufs x 512 floats)
    //         [4096,8192) = V area (same layout)
    // Epilogue reuses [0,4096) and [4096,8192) as two 64x64 partials.
    __shared__ float smem[8192];

    const int t    = threadIdx.x;
    const int w    = t >> 6;        // wave id 0..3
    const int lane = t & 63;
    const int tk   = lane >> 3;     // k-group: rows tk*8..tk*8+7 of output
    const int tv   = lane & 7;      // v-group: cols tv*8..tv*8+7
    const int chunk = blockIdx.x;
    const int h     = blockIdx.y;

    float* kb = smem + w * 1024;          // this wave's K double-buffer
    float* vb = smem + 4096 + w * 1024;   // this wave's V double-buffer

    const int row0 = chunk * RPB + w * RPW;   // wave's first s-row
    const int sr = lane >> 4;                 // staging row 0..3 (and +4)
    const int sc = (lane & 15) * 4;           // staging col

    float acc[8][8];
    #pragma unroll
    for (int i = 0; i < 8; ++i)
        #pragma unroll
        for (int j = 0; j < 8; ++j) acc[i][j] = 0.f;

    float4 kr0, kr1, vr0, vr1;
    float w0, w1;

    // ---- prologue: load + stage tile 0 into buf 0 ----
    {
        int r = row0;
        const float* kp = keys   + ((r + sr) * HH + h) * DK + sc;
        const float* vp = values + ((r + sr) * HH + h) * DV + sc;
        kr0 = *(const float4*)kp;
        kr1 = *(const float4*)(kp + 4 * HH * DK);
        vr0 = *(const float4*)vp;
        vr1 = *(const float4*)(vp + 4 * HH * DV);
        w0 = rho[r + sr];
        w1 = rho[r + sr + 4];
        kr0.x *= w0; kr0.y *= w0; kr0.z *= w0; kr0.w *= w0;
        kr1.x *= w1; kr1.y *= w1; kr1.z *= w1; kr1.w *= w1;
        // LDS offset: row sr, col sc -> sr*64+sc == lane*4 (contiguous per lane)
        *(float4*)(kb + lane * 4)       = kr0;
        *(float4*)(kb + 256 + lane * 4) = kr1;
        *(float4*)(vb + lane * 4)       = vr0;
        *(float4*)(vb + 256 + lane * 4) = vr1;
    }

    for (int tile = 0; tile < NT; ++tile) {
        const int cur = tile & 1;
        const int nxt = cur ^ 1;
        const bool more = (tile + 1) < NT;

        // issue next tile's global loads early (covered by 512 FMAs below)
        if (more) {
            int r = row0 + (tile + 1) * TR;
            const float* kp = keys   + ((r + sr) * HH + h) * DK + sc;
            const float* vp = values + ((r + sr) * HH + h) * DV + sc;
            kr0 = *(const float4*)kp;
            kr1 = *(const float4*)(kp + 4 * HH * DK);
            vr0 = *(const float4*)vp;
            vr1 = *(const float4*)(vp + 4 * HH * DV);
            w0 = rho[r + sr];
            w1 = rho[r + sr + 4];
        }

        const float* kc = kb + cur * 512;
        const float* vc = vb + cur * 512;
        #pragma unroll
        for (int s = 0; s < TR; ++s) {
            float4 ka  = *(const float4*)(kc + s * 64 + tk * 8);
            float4 ka2 = *(const float4*)(kc + s * 64 + tk * 8 + 4);
            float4 va  = *(const float4*)(vc + s * 64 + tv * 8);
            float4 va2 = *(const float4*)(vc + s * 64 + tv * 8 + 4);
            float kv[8] = {ka.x, ka.y, ka.z, ka.w, ka2.x, ka2.y, ka2.z, ka2.w};
            float vv[8] = {va.x, va.y, va.z, va.w, va2.x, va2.y, va2.z, va2.w};
            #pragma unroll
            for (int i = 0; i < 8; ++i)
                #pragma unroll
                for (int j = 0; j < 8; ++j)
                    acc[i][j] = fmaf(kv[i], vv[j], acc[i][j]);
        }

        // stage next tile (buffer nxt was last read one iteration ago by THIS
        // wave only -> program order suffices, no barrier)
        if (more) {
            kr0.x *= w0; kr0.y *= w0; kr0.z *= w0; kr0.w *= w0;
            kr1.x *= w1; kr1.y *= w1; kr1.z *= w1; kr1.w *= w1;
            float* kn = kb + nxt * 512;
            float* vn = vb + nxt * 512;
            *(float4*)(kn + lane * 4)       = kr0;
            *(float4*)(kn + 256 + lane * 4) = kr1;
            *(float4*)(vn + lane * 4)       = vr0;
            *(float4*)(vn + 256 + lane * 4) = vr1;
        }
    }

    // ---- epilogue: cross-wave reduce in LDS, then coalesced atomics ----
    __syncthreads();   // everyone done with staging buffers before reuse
    float* red0 = smem;
    float* red1 = smem + 4096;

    if (w < 2) {
        float* dst = (w == 0) ? red0 : red1;
        #pragma unroll
        for (int i = 0; i < 8; ++i) {
            float4 a0 = {acc[i][0], acc[i][1], acc[i][2], acc[i][3]};
            float4 a1 = {acc[i][4], acc[i][5], acc[i][6], acc[i][7]};
            *(float4*)(dst + (tk * 8 + i) * 64 + tv * 8)     = a0;
            *(float4*)(dst + (tk * 8 + i) * 64 + tv * 8 + 4) = a1;
        }
    }
    __syncthreads();
    if (w >= 2) {
        float* dst = (w == 2) ? red0 : red1;
        #pragma unroll
        for (int i = 0; i < 8; ++i) {
            float4* p0 = (float4*)(dst + (tk * 8 + i) * 64 + tv * 8);
            float4* p1 = p0 + 1;
            float4 c0 = *p0, c1 = *p1;
            c0.x += acc[i][0]; c0.y += acc[i][1]; c0.z += acc[i][2]; c0.w += acc[i][3];
            c1.x += acc[i][4]; c1.y += acc[i][5]; c1.z += acc[i][6]; c1.w += acc[i][7];
            *p0 = c0; *p1 = c1;
        }
    }
    __syncthreads();

    float* o = out + h * (DK * DV);
    #pragma unroll
    for (int i = 0; i < 16; ++i) {
        int idx = i * 256 + t;
        atomicAdd(o + idx, red0[idx] + red1[idx]);
    }
}

extern "C" void kernel_launch(void* const* d_in, const int* in_sizes, int n_in,
                              void* d_out, int out_size, void* d_ws, size_t ws_size,
                              hipStream_t stream) {
    const float* mem    = (const float*)d_in[0];  // (H, Dk, Dv)
    const float* keys   = (const float*)d_in[1];  // (B, S, H, Dk)
    const float* values = (const float*)d_in[2];  // (B, S, H, Dv)
    const float* rho    = (const float*)d_in[3];  // (B, S)
    float* out = (float*)d_out;                   // (H, Dk, Dv)

    init_out<<<dim3((HH * DK * DV) / 256), dim3(256), 0, stream>>>(mem, out);

    dim3 grid(NCHUNK, HH);
    accum<<<grid, dim3(256), 0, stream>>>(keys, values, rho, out);
}

// Round 3
// 165.941 us; speedup vs baseline: 1.0134x; 1.0134x over previous
//
#include <hip/hip_runtime.h>

// out[h,k,v] = 0.95*M[h,k,v] + sum_{b,s} rho[b,s]*K[b,s,h,k]*V[b,s,h,v]
// B=4, S=4096 (ROWS=16384), H=16, Dk=Dv=64. fp32 (no fp32 MFMA on CDNA4).
//
// R3: block = (s-chunk, head), 4 waves split s within each staged 32-row tile.
// Staging via global_load_lds DMA (no staging VGPRs), shared double buffer,
// ONE barrier per tile. 8x8 per-thread register tile (4 ds_read_b128 per
// 64 FMA). rho folded into k-fragment. Epilogue: 4 wave-partials pairwise
// reduced in LDS, then fully-coalesced atomics.

constexpr int HH = 16;
constexpr int DK = 64;
constexpr int DV = 64;
constexpr int ROWS = 16384;
constexpr int NCHUNK = 64;
constexpr int RPB = ROWS / NCHUNK;   // 256 rows per block
constexpr int TSR = 32;              // rows per staged tile
constexpr int NT = RPB / TSR;        // 8 tiles
constexpr float DECAY = 0.95f;

__global__ __launch_bounds__(256) void init_out(const float* __restrict__ mem,
                                                float* __restrict__ out) {
    int i = blockIdx.x * 256 + threadIdx.x;
    out[i] = DECAY * mem[i];
}

__device__ __forceinline__ void dma16(const float* g, float* l) {
    __builtin_amdgcn_global_load_lds(
        (const __attribute__((address_space(1))) void*)g,
        (__attribute__((address_space(3))) void*)l, 16, 0, 0);
}

__global__ __launch_bounds__(256) void accum(const float* __restrict__ keys,
                                             const float* __restrict__ values,
                                             const float* __restrict__ rho,
                                             float* __restrict__ out) {
    __shared__ float sK[2][TSR * DK];   // 16 KiB
    __shared__ float sV[2][TSR * DV];   // 16 KiB
    __shared__ float sR[RPB];           // 1 KiB

    const int t    = threadIdx.x;
    const int w    = t >> 6;
    const int lane = t & 63;
    const int tk   = lane >> 3;   // k-group (rows tk*8..+7)
    const int tv   = lane & 7;    // v-group (cols tv*8..+7)
    const int chunk = blockIdx.x;
    const int h     = blockIdx.y;
    const int row0  = chunk * RPB;

    // DMA addressing: thread t stages float4 #t of each 4 KB half-tile.
    const int dr = t >> 4;          // row within half-tile: 0..15
    const int dc = (t & 15) * 4;    // col: 0..60

    // rho for the whole chunk (256 floats, one size=4 DMA per thread)
    __builtin_amdgcn_global_load_lds(
        (const __attribute__((address_space(1))) void*)(rho + row0 + t),
        (__attribute__((address_space(3))) void*)(sR + t), 4, 0, 0);

    // prologue: stage tile 0 into buffer 0
    {
        const float* kg = keys   + ((size_t)(row0 + dr) * HH + h) * DK + dc;
        const float* vg = values + ((size_t)(row0 + dr) * HH + h) * DV + dc;
        dma16(kg, &sK[0][dr * DK + dc]);
        dma16(kg + 16 * HH * DK, &sK[0][(dr + 16) * DK + dc]);
        dma16(vg, &sV[0][dr * DV + dc]);
        dma16(vg + 16 * HH * DV, &sV[0][(dr + 16) * DV + dc]);
    }

    float4 acc[8][2];
    #pragma unroll
    for (int i = 0; i < 8; ++i) {
        acc[i][0] = make_float4(0.f, 0.f, 0.f, 0.f);
        acc[i][1] = make_float4(0.f, 0.f, 0.f, 0.f);
    }

    __syncthreads();   // tile 0 + rho staged

    for (int tile = 0; tile < NT; ++tile) {
        const int cur = tile & 1;
        const int nxt = cur ^ 1;

        if (tile + 1 < NT) {
            const int r = row0 + (tile + 1) * TSR + dr;
            const float* kg = keys   + ((size_t)r * HH + h) * DK + dc;
            const float* vg = values + ((size_t)r * HH + h) * DV + dc;
            dma16(kg, &sK[nxt][dr * DK + dc]);
            dma16(kg + 16 * HH * DK, &sK[nxt][(dr + 16) * DK + dc]);
            dma16(vg, &sV[nxt][dr * DV + dc]);
            dma16(vg + 16 * HH * DV, &sV[nxt][(dr + 16) * DV + dc]);
        }

        // wave w computes s-rows [w*8, w*8+8) of this tile
        const float* kb = &sK[cur][w * 8 * DK];
        const float* vb = &sV[cur][w * 8 * DV];
        const float* rb = &sR[tile * TSR + w * 8];

        #pragma unroll
        for (int si = 0; si < 8; ++si) {
            float4 kf  = *(const float4*)(kb + si * DK + tk * 8);
            float4 kf2 = *(const float4*)(kb + si * DK + tk * 8 + 4);
            float4 vf  = *(const float4*)(vb + si * DV + tv * 8);
            float4 vf2 = *(const float4*)(vb + si * DV + tv * 8 + 4);
            float r = rb[si];   // wave-uniform broadcast read
            kf.x *= r; kf.y *= r; kf.z *= r; kf.w *= r;
            kf2.x *= r; kf2.y *= r; kf2.z *= r; kf2.w *= r;

            #define FMA_ROW(I, KV)                                  \
                acc[I][0].x = fmaf(KV, vf.x,  acc[I][0].x);         \
                acc[I][0].y = fmaf(KV, vf.y,  acc[I][0].y);         \
                acc[I][0].z = fmaf(KV, vf.z,  acc[I][0].z);         \
                acc[I][0].w = fmaf(KV, vf.w,  acc[I][0].w);         \
                acc[I][1].x = fmaf(KV, vf2.x, acc[I][1].x);         \
                acc[I][1].y = fmaf(KV, vf2.y, acc[I][1].y);         \
                acc[I][1].z = fmaf(KV, vf2.z, acc[I][1].z);         \
                acc[I][1].w = fmaf(KV, vf2.w, acc[I][1].w);
            FMA_ROW(0, kf.x)  FMA_ROW(1, kf.y)  FMA_ROW(2, kf.z)  FMA_ROW(3, kf.w)
            FMA_ROW(4, kf2.x) FMA_ROW(5, kf2.y) FMA_ROW(6, kf2.z) FMA_ROW(7, kf2.w)
            #undef FMA_ROW
        }

        __syncthreads();   // drains DMA(nxt); all waves done reading cur
    }

    // ---- epilogue: pairwise-reduce 4 wave-partials into 2, then atomics ----
    float* red = (w & 1) ? &sV[0][0] : &sK[0][0];   // each 4096 floats

    if (w < 2) {
        #pragma unroll
        for (int i = 0; i < 8; ++i) {
            *(float4*)(red + (tk * 8 + i) * 64 + tv * 8)     = acc[i][0];
            *(float4*)(red + (tk * 8 + i) * 64 + tv * 8 + 4) = acc[i][1];
        }
    }
    __syncthreads();
    if (w >= 2) {
        #pragma unroll
        for (int i = 0; i < 8; ++i) {
            float4* p0 = (float4*)(red + (tk * 8 + i) * 64 + tv * 8);
            float4* p1 = p0 + 1;
            float4 c0 = *p0, c1 = *p1;
            c0.x += acc[i][0].x; c0.y += acc[i][0].y;
            c0.z += acc[i][0].z; c0.w += acc[i][0].w;
            c1.x += acc[i][1].x; c1.y += acc[i][1].y;
            c1.z += acc[i][1].z; c1.w += acc[i][1].w;
            *p0 = c0; *p1 = c1;
        }
    }
    __syncthreads();

    float* o = out + h * (DK * DV);
    const float* r0 = &sK[0][0];
    const float* r1 = &sV[0][0];
    #pragma unroll
    for (int i = 0; i < 16; ++i) {
        int idx = i * 256 + t;
        atomicAdd(o + idx, r0[idx] + r1[idx]);
    }
}

extern "C" void kernel_launch(void* const* d_in, const int* in_sizes, int n_in,
                              void* d_out, int out_size, void* d_ws, size_t ws_size,
                              hipStream_t stream) {
    const float* mem    = (const float*)d_in[0];  // (H, Dk, Dv)
    const float* keys   = (const float*)d_in[1];  // (B, S, H, Dk)
    const float* values = (const float*)d_in[2];  // (B, S, H, Dv)
    const float* rho    = (const float*)d_in[3];  // (B, S)
    float* out = (float*)d_out;                   // (H, Dk, Dv)

    init_out<<<dim3((HH * DK * DV) / 256), dim3(256), 0, stream>>>(mem, out);

    dim3 grid(NCHUNK, HH);
    accum<<<grid, dim3(256), 0, stream>>>(keys, values, rho, out);
}